// Round 7
// baseline (10395.195 us; speedup 1.0000x reference)
//
#include <hip/hip_runtime.h>
#include <stdint.h>

typedef unsigned long long u64;

#define NBATCH 32
#define NPTS   131072
#define KBLK   16                // blocks per batch
#define PPB    (NPTS / KBLK)     // 8192 points per block (2^13)
#define NTHR   1024
#define NWAVE  (NTHR / 64)       // 16 waves
#define PPT    (PPB / NTHR)      // 8 points per thread
#define FLT_MAX_C 3.402823466e+38f

// ws: per (batch, block, parity) one 64B slot of 8 u64.  (64 KB total)
// words 0..2: ((u64)s<<32) | float_bits(x|y|z)   -- self-tagged, relaxed
// word  3   : ((u64)s<<49) | dist_bits<<17 | (131071-idx)
//   dist>=0 -> float bits monotone as uint; idx inverted so u64-max gives
//   first-occurrence argmax (np.argmax tie-break). 0xAA poison / stale tags
//   never equal live s -> no ws init; parity double-buffer, skew<=1 proof
//   (producer can only rewrite parity p at s+2, which requires every
//   consumer to have finished reading step s).  Validated r2/r4/r5/r6.
__device__ __forceinline__ u64* slot_ptr(u64* slots, int b, int k, int par) {
    return slots + ((size_t)((b * KBLK + k) * 2 + par)) * 8;
}

// 8 waves/EU min -> 64-unified-reg budget; persistent state (32 floats) +
// working set (~25) fits, so the allocator has no pressure reason to split
// into AGPRs (the v_accvgpr shuttle that inflated VALU 2.15x in r1..r6).
__global__ __launch_bounds__(NTHR, 8)
void fps_kernel(const float* __restrict__ points, int* __restrict__ out,
                u64* __restrict__ slots, int S)
{
    const int b    = blockIdx.x & (NBATCH - 1);  // batch
    const int kk   = blockIdx.x >> 5;            // 0..15; b%8 fixed -> 1 XCD
    const int t    = threadIdx.x;
    const int lane = t & 63;
    const int wv   = t >> 6;

    const float* pb = points + (size_t)b * 3 * NPTS;
    const float* bx = pb + kk * PPB;
    const float* by = bx + NPTS;
    const float* bz = bx + 2 * NPTS;

    float px[PPT], py[PPT], pz[PPT], md[PPT];   // 32 persistent floats
    const int t4 = t * 4;
#pragma unroll
    for (int c = 0; c < PPT / 4; ++c) {
        float4 vx = *(const float4*)(bx + c * (NTHR * 4) + t4);
        float4 vy = *(const float4*)(by + c * (NTHR * 4) + t4);
        float4 vz = *(const float4*)(bz + c * (NTHR * 4) + t4);
        px[c*4+0]=vx.x; px[c*4+1]=vx.y; px[c*4+2]=vx.z; px[c*4+3]=vx.w;
        py[c*4+0]=vy.x; py[c*4+1]=vy.y; py[c*4+2]=vy.z; py[c*4+3]=vy.w;
        pz[c*4+0]=vz.x; pz[c*4+1]=vz.y; pz[c*4+2]=vz.z; pz[c*4+3]=vz.w;
        md[c*4+0]=FLT_MAX_C; md[c*4+1]=FLT_MAX_C;
        md[c*4+2]=FLT_MAX_C; md[c*4+3]=FLT_MAX_C;
    }

    __shared__ float s_v[NWAVE];
    __shared__ int   s_i[NWAVE];
    __shared__ int   s_bi;          // block-winner idx (for owner extract)
    __shared__ unsigned s_bc[3];    // next centroid xbits,ybits,zbits

    float cx = pb[0], cy = pb[NPTS], cz = pb[2 * NPTS];
    if (kk == 0 && t == 0) out[(size_t)b * S] = 0;

    for (int s = 1; s < S; ++s) {
        // ---- scan: exact np fp32 semantics (no fma), ascending-index '>'
        float bestv = -1.0f;
        int   bestp = 0;
#pragma unroll
        for (int p = 0; p < PPT; ++p) {
            float dx = __fsub_rn(px[p], cx);
            float dy = __fsub_rn(py[p], cy);
            float dz = __fsub_rn(pz[p], cz);
            float d  = __fadd_rn(__fadd_rn(__fmul_rn(dx, dx), __fmul_rn(dy, dy)),
                                 __fmul_rn(dz, dz));
            float m  = fminf(md[p], d);
            md[p] = m;
            bool tk = m > bestv;
            bestv = tk ? m : bestv;
            bestp = tk ? p : bestp;
        }
        int gidx = kk * PPB + (bestp >> 2) * (NTHR * 4) + t4 + (bestp & 3);

        // ---- wave reduce, tie -> lower index
#pragma unroll
        for (int off = 32; off >= 1; off >>= 1) {
            float ov = __shfl_down(bestv, off);
            int   oi = __shfl_down(gidx, off);
            bool tk = (ov > bestv) || (ov == bestv && oi < gidx);
            bestv = tk ? ov : bestv;
            gidx  = tk ? oi : gidx;
        }
        if (lane == 0) { s_v[wv] = bestv; s_i[wv] = gidx; }
        __syncthreads();   // barrier 1: partials ready

        // ---- cross-wave reduce in wave 0; publish di word (relaxed)
        if (wv == 0) {
            float v16 = (lane < NWAVE) ? s_v[lane] : -1.0f;
            int   i16 = (lane < NWAVE) ? s_i[lane] : 0x7fffffff;
#pragma unroll
            for (int off = 8; off >= 1; off >>= 1) {
                float ov = __shfl_down(v16, off);
                int   oi = __shfl_down(i16, off);
                bool tk = (ov > v16) || (ov == v16 && oi < i16);
                v16 = tk ? ov : v16;
                i16 = tk ? oi : i16;
            }
            if (lane == 0) {
                u64 di = ((u64)(unsigned)s << 49)
                       | ((u64)__float_as_uint(v16) << 17)
                       | (u64)(unsigned)(131071 - i16);
                __hip_atomic_store(slot_ptr(slots, b, kk, s & 1) + 3, di,
                                   __ATOMIC_RELAXED, __HIP_MEMORY_SCOPE_AGENT);
                s_bi = i16;
            }
        }
        __syncthreads();   // barrier 2: s_bi ready

        // ---- owner thread ships the block-winner coords (self-tagged words)
        int widx = s_bi;
        if ((widx >> 13) == kk) {                     // PPB = 2^13
            int l = widx & (PPB - 1);
            if (t == ((l >> 2) & (NTHR - 1))) {
                int pw = ((l >> 12) << 2) | (l & 3);  // c*4 + j, c = l>>12
                float wx = 0.f, wy = 0.f, wz = 0.f;
#pragma unroll
                for (int p = 0; p < PPT; ++p) {       // constant-index select
                    bool e = (p == pw);
                    wx = e ? px[p] : wx; wy = e ? py[p] : wy; wz = e ? pz[p] : wz;
                }
                u64 tg = (u64)(unsigned)s << 32;
                u64* sp = slot_ptr(slots, b, kk, s & 1);
                __hip_atomic_store(sp + 0, tg | __float_as_uint(wx),
                                   __ATOMIC_RELAXED, __HIP_MEMORY_SCOPE_AGENT);
                __hip_atomic_store(sp + 1, tg | __float_as_uint(wy),
                                   __ATOMIC_RELAXED, __HIP_MEMORY_SCOPE_AGENT);
                __hip_atomic_store(sp + 2, tg | __float_as_uint(wz),
                                   __ATOMIC_RELAXED, __HIP_MEMORY_SCOPE_AGENT);
            }
        }

        // ---- wave 0: poll 16 blocks x 4 words = 64 lanes, tag-matched
        if (wv == 0) {
            u64* ps = slot_ptr(slots, b, lane >> 2, s & 1) + (lane & 3);
            const int sh = ((lane & 3) == 3) ? 49 : 32;
            u64 got;
            do {
                got = __hip_atomic_load(ps, __ATOMIC_RELAXED,
                                        __HIP_MEMORY_SCOPE_AGENT);
            } while ((int)(got >> sh) != s);
            // broadcast each block's di word to its 4 lanes, butterfly max
            u64 dv = (u64)__shfl((long long)got, lane | 3);
#pragma unroll
            for (int off = 1; off <= 32; off <<= 1) {
                u64 o = (u64)__shfl_xor((long long)dv, off);
                dv = (o > dv) ? o : dv;
            }
            // winner's word-3 lane (unique di: idx in low bits)
            u64 mask = __ballot(((lane & 3) == 3) && (got == dv));
            int wb4 = (__ffsll((long long)mask) - 1) & ~3;
            unsigned lo = (unsigned)got;
            unsigned cxb = (unsigned)__shfl((int)lo, wb4 + 0);
            unsigned cyb = (unsigned)__shfl((int)lo, wb4 + 1);
            unsigned czb = (unsigned)__shfl((int)lo, wb4 + 2);
            if (lane == 0) {
                s_bc[0] = cxb; s_bc[1] = cyb; s_bc[2] = czb;
                if (kk == 0) out[(size_t)b * S + s] = 131071 - (int)(dv & 0x1FFFF);
            }
        }
        __syncthreads();   // barrier 3: result broadcast ready
        cx = __uint_as_float(s_bc[0]);
        cy = __uint_as_float(s_bc[1]);
        cz = __uint_as_float(s_bc[2]);
    }
}

extern "C" void kernel_launch(void* const* d_in, const int* in_sizes, int n_in,
                              void* d_out, int out_size, void* d_ws, size_t ws_size,
                              hipStream_t stream) {
    const float* points = (const float*)d_in[0];
    int* out   = (int*)d_out;
    u64* slots = (u64*)d_ws;              // 32*16*2*64B = 64 KB
    int S = out_size / NBATCH;            // 2048
    // 512 blocks x 16 waves, 64-reg cap -> exactly 2 blocks/CU on 256 CUs:
    // all co-resident (spin-exchange safe), and the second block's scan
    // hides the first block's barrier/poll stalls.
    fps_kernel<<<dim3(NBATCH * KBLK), dim3(NTHR), 0, stream>>>(points, out, slots, S);
}